// Round 3
// baseline (219.311 us; speedup 1.0000x reference)
//
#include <hip/hip_runtime.h>

// One thread per point. Constants C2 (3,3,5)=45 f32 and C3 (3,3,3,7)=189 f32
// staged in LDS (uniform-address reads broadcast, conflict-free).
__global__ __launch_bounds__(256) void hop_invariant_kernel(
    const float* __restrict__ tf,   // (N,16)
    const float* __restrict__ C2g,  // 45
    const float* __restrict__ C3g,  // 189
    float* __restrict__ out,        // (N,13)
    int n_points)
{
    __shared__ float lC2[45];   // lC2[(i*3+j)*5+m] = C2[i][j][m]
    __shared__ float lC3[189];  // lC3[((i*3+j)*3+k)*7+m] = C3[i][j][k][m]
    int tid = threadIdx.x;
    if (tid < 45) lC2[tid] = C2g[tid];
    else if (tid < 234) lC3[tid - 45] = C3g[tid - 45];
    __syncthreads();

    int n = blockIdx.x * blockDim.x + tid;
    if (n >= n_points) return;

    const float4* fp = reinterpret_cast<const float4*>(tf + (size_t)n * 16);
    float4 f0 = fp[0], f1 = fp[1], f2 = fp[2], f3 = fp[3];
    float s = f0.x;
    float v[3] = {f0.y, f0.z, f0.w};
    float q[5] = {f1.x, f1.y, f1.z, f1.w, f2.x};
    float t[7] = {f2.y, f2.z, f2.w, f3.x, f3.y, f3.z, f3.w};

    float I0 = s;
    float I1 = v[0]*v[0] + v[1]*v[1] + v[2]*v[2];

    // a_half (flat p = i*3+j): ah[p] = sum_m q[m]*C2[i][j][m]
    float ah[9];
    #pragma unroll
    for (int p = 0; p < 9; ++p) {
        float acc = 0.f;
        #pragma unroll
        for (int m = 0; m < 5; ++m) acc = fmaf(q[m], lC2[p*5+m], acc);
        ah[p] = acc;
    }

    // a[j][k] = sum_i ah[i][j]*ah[i][k]  (symmetric)
    float a[3][3];
    #pragma unroll
    for (int j = 0; j < 3; ++j)
        #pragma unroll
        for (int k = j; k < 3; ++k) {
            float acc = 0.f;
            #pragma unroll
            for (int i = 0; i < 3; ++i) acc = fmaf(ah[i*3+j], ah[i*3+k], acc);
            a[j][k] = acc; a[k][j] = acc;
        }
    float I2 = a[0][0] + a[1][1] + a[2][2];

    // I3 = sum_m q[m] * (sum_p a[p/3][p%3]*C2flat[p][m])
    float I3 = 0.f;
    #pragma unroll
    for (int m = 0; m < 5; ++m) {
        float acc = 0.f;
        #pragma unroll
        for (int p = 0; p < 9; ++p) acc = fmaf(a[p/3][p%3], lC2[p*5+m], acc);
        I3 = fmaf(acc, q[m], I3);
    }

    // cvec[j] = sum_i ah[i][j]*v[i]
    float cv[3];
    #pragma unroll
    for (int j = 0; j < 3; ++j)
        cv[j] = fmaf(ah[6+j], v[2], fmaf(ah[3+j], v[1], ah[j]*v[0]));
    float I6 = cv[0]*v[0] + cv[1]*v[1] + cv[2]*v[2];
    float I7 = cv[0]*cv[0] + cv[1]*cv[1] + cv[2]*cv[2];

    // b_half (flat r = (i*3+j)*3+k): bh[r] = sum_m t[m]*C3[i][j][k][m]
    float bh[27];
    #pragma unroll
    for (int r = 0; r < 27; ++r) {
        float acc = 0.f;
        #pragma unroll
        for (int m = 0; m < 7; ++m) acc = fmaf(t[m], lC3[r*7+m], acc);
        bh[r] = acc;
    }

    // b[k][l] = sum_{p=0..8} bh[p*3+k]*bh[p*3+l]  (symmetric)
    float b[3][3];
    #pragma unroll
    for (int k = 0; k < 3; ++k)
        #pragma unroll
        for (int l = k; l < 3; ++l) {
            float acc = 0.f;
            #pragma unroll
            for (int p = 0; p < 9; ++p) acc = fmaf(bh[p*3+k], bh[p*3+l], acc);
            b[k][l] = acc; b[l][k] = acc;
        }
    float I4 = b[0][0] + b[1][1] + b[2][2];

    // I8 = sum_{ij} v[i]*v[j]*d[i][j], d[i][j] = sum_k bh[(i*3+j)*3+k]*v[k]
    float I8 = 0.f;
    #pragma unroll
    for (int i = 0; i < 3; ++i)
        #pragma unroll
        for (int j = 0; j < 3; ++j) {
            int p = i*3 + j;
            float dv = fmaf(bh[p*3+2], v[2], fmaf(bh[p*3+1], v[1], bh[p*3+0]*v[0]));
            I8 = fmaf(v[i]*v[j], dv, I8);
        }

    // I10 = sum_m q[m] * (sum_p b[p/3][p%3]*C2flat[p][m])
    float I10 = 0.f;
    #pragma unroll
    for (int m = 0; m < 5; ++m) {
        float acc = 0.f;
        #pragma unroll
        for (int p = 0; p < 9; ++p) acc = fmaf(b[p/3][p%3], lC2[p*5+m], acc);
        I10 = fmaf(acc, q[m], I10);
    }

    float I5 = 0.f, I9 = 0.f, I11 = 0.f;
    #pragma unroll
    for (int k = 0; k < 3; ++k)
        #pragma unroll
        for (int l = 0; l < 3; ++l) {
            I5  = fmaf(b[k][l], b[k][l], I5);
            I9  = fmaf(v[k]*v[l], b[k][l], I9);
            I11 = fmaf(b[k][l], a[k][l], I11);
        }

    // e[k] = sum_p bh[p*3+k]*ah[p]  (I12 simplification:
    // e[k] = sum_p e_half[k][p]*q[p] = sum_{ij} b_half[i][j][k]*a_half[i][j])
    float e0 = 0.f, e1 = 0.f, e2 = 0.f;
    #pragma unroll
    for (int p = 0; p < 9; ++p) {
        e0 = fmaf(bh[p*3+0], ah[p], e0);
        e1 = fmaf(bh[p*3+1], ah[p], e1);
        e2 = fmaf(bh[p*3+2], ah[p], e2);
    }
    float I12 = e0*e0 + e1*e1 + e2*e2;

    float* o = out + (size_t)n * 13;
    o[0]  = I0;  o[1]  = I1;  o[2]  = I2;  o[3]  = I3;
    o[4]  = I4;  o[5]  = I5;  o[6]  = I6;  o[7]  = I7;
    o[8]  = I8;  o[9]  = I9;  o[10] = I10; o[11] = I11;
    o[12] = I12;
}

extern "C" void kernel_launch(void* const* d_in, const int* in_sizes, int n_in,
                              void* d_out, int out_size, void* d_ws, size_t ws_size,
                              hipStream_t stream) {
    const float* tf  = (const float*)d_in[0];
    const float* C2g = (const float*)d_in[1];
    const float* C3g = (const float*)d_in[2];
    float* out = (float*)d_out;
    int n_points = in_sizes[0] / 16;

    int block = 256;
    int grid = (n_points + block - 1) / block;
    hop_invariant_kernel<<<grid, block, 0, stream>>>(tf, C2g, C3g, out, n_points);
}

// Round 9
// 214.787 us; speedup vs baseline: 1.0211x; 1.0211x over previous
//
#include <hip/hip_runtime.h>

// One thread per point; constants in LDS (uniform broadcast reads);
// outputs staged in LDS then written back fully coalesced
// (13 wave-contiguous dword stores per block instead of 13 strided scatters).
__global__ __launch_bounds__(256) void hop_invariant_kernel(
    const float* __restrict__ tf,   // (N,16)
    const float* __restrict__ C2g,  // 45
    const float* __restrict__ C3g,  // 189
    float* __restrict__ out,        // (N,13)
    int n_points)
{
    __shared__ float lC2[45];        // lC2[(i*3+j)*5+m]
    __shared__ float lC3[189];       // lC3[((i*3+j)*3+k)*7+m]
    __shared__ float lOut[256 * 13]; // [local_point][invariant], 13.3 KB
    int tid = threadIdx.x;
    if (tid < 45) lC2[tid] = C2g[tid];
    else if (tid < 234) lC3[tid - 45] = C3g[tid - 45];
    __syncthreads();

    int block_base = blockIdx.x * 256;
    int n = block_base + tid;

    if (n < n_points) {
        const float4* fp = reinterpret_cast<const float4*>(tf + (size_t)n * 16);
        float4 f0 = fp[0], f1 = fp[1], f2 = fp[2], f3 = fp[3];
        float s = f0.x;
        float v[3] = {f0.y, f0.z, f0.w};
        float q[5] = {f1.x, f1.y, f1.z, f1.w, f2.x};
        float t[7] = {f2.y, f2.z, f2.w, f3.x, f3.y, f3.z, f3.w};

        float I0 = s;
        float I1 = v[0]*v[0] + v[1]*v[1] + v[2]*v[2];

        // a_half (flat p = i*3+j): ah[p] = sum_m q[m]*C2[i][j][m]
        float ah[9];
        #pragma unroll
        for (int p = 0; p < 9; ++p) {
            float acc = 0.f;
            #pragma unroll
            for (int m = 0; m < 5; ++m) acc = fmaf(q[m], lC2[p*5+m], acc);
            ah[p] = acc;
        }

        // a[j][k] = sum_i ah[i][j]*ah[i][k]  (symmetric)
        float a[3][3];
        #pragma unroll
        for (int j = 0; j < 3; ++j)
            #pragma unroll
            for (int k = j; k < 3; ++k) {
                float acc = 0.f;
                #pragma unroll
                for (int i = 0; i < 3; ++i) acc = fmaf(ah[i*3+j], ah[i*3+k], acc);
                a[j][k] = acc; a[k][j] = acc;
            }
        float I2 = a[0][0] + a[1][1] + a[2][2];

        // I3 = sum_m q[m] * (sum_p a[p/3][p%3]*C2flat[p][m])
        float I3 = 0.f;
        #pragma unroll
        for (int m = 0; m < 5; ++m) {
            float acc = 0.f;
            #pragma unroll
            for (int p = 0; p < 9; ++p) acc = fmaf(a[p/3][p%3], lC2[p*5+m], acc);
            I3 = fmaf(acc, q[m], I3);
        }

        // cvec[j] = sum_i ah[i][j]*v[i]
        float cv[3];
        #pragma unroll
        for (int j = 0; j < 3; ++j)
            cv[j] = fmaf(ah[6+j], v[2], fmaf(ah[3+j], v[1], ah[j]*v[0]));
        float I6 = cv[0]*v[0] + cv[1]*v[1] + cv[2]*v[2];
        float I7 = cv[0]*cv[0] + cv[1]*cv[1] + cv[2]*cv[2];

        // b_half (flat r = (i*3+j)*3+k): bh[r] = sum_m t[m]*C3[i][j][k][m]
        float bh[27];
        #pragma unroll
        for (int r = 0; r < 27; ++r) {
            float acc = 0.f;
            #pragma unroll
            for (int m = 0; m < 7; ++m) acc = fmaf(t[m], lC3[r*7+m], acc);
            bh[r] = acc;
        }

        // b[k][l] = sum_{p=0..8} bh[p*3+k]*bh[p*3+l]  (symmetric)
        float b[3][3];
        #pragma unroll
        for (int k = 0; k < 3; ++k)
            #pragma unroll
            for (int l = k; l < 3; ++l) {
                float acc = 0.f;
                #pragma unroll
                for (int p = 0; p < 9; ++p) acc = fmaf(bh[p*3+k], bh[p*3+l], acc);
                b[k][l] = acc; b[l][k] = acc;
            }
        float I4 = b[0][0] + b[1][1] + b[2][2];

        // I8 = sum_{ij} v[i]*v[j]*(sum_k bh[(i*3+j)*3+k]*v[k])
        float I8 = 0.f;
        #pragma unroll
        for (int i = 0; i < 3; ++i)
            #pragma unroll
            for (int j = 0; j < 3; ++j) {
                int p = i*3 + j;
                float dv = fmaf(bh[p*3+2], v[2], fmaf(bh[p*3+1], v[1], bh[p*3+0]*v[0]));
                I8 = fmaf(v[i]*v[j], dv, I8);
            }

        // I10 = sum_m q[m] * (sum_p b[p/3][p%3]*C2flat[p][m])
        float I10 = 0.f;
        #pragma unroll
        for (int m = 0; m < 5; ++m) {
            float acc = 0.f;
            #pragma unroll
            for (int p = 0; p < 9; ++p) acc = fmaf(b[p/3][p%3], lC2[p*5+m], acc);
            I10 = fmaf(acc, q[m], I10);
        }

        float I5 = 0.f, I9 = 0.f, I11 = 0.f;
        #pragma unroll
        for (int k = 0; k < 3; ++k)
            #pragma unroll
            for (int l = 0; l < 3; ++l) {
                I5  = fmaf(b[k][l], b[k][l], I5);
                I9  = fmaf(v[k]*v[l], b[k][l], I9);
                I11 = fmaf(b[k][l], a[k][l], I11);
            }

        // e[k] = sum_p bh[p*3+k]*ah[p]  (I12: e = sum_ij b_half[ij][k]*a_half[ij])
        float e0 = 0.f, e1 = 0.f, e2 = 0.f;
        #pragma unroll
        for (int p = 0; p < 9; ++p) {
            e0 = fmaf(bh[p*3+0], ah[p], e0);
            e1 = fmaf(bh[p*3+1], ah[p], e1);
            e2 = fmaf(bh[p*3+2], ah[p], e2);
        }
        float I12 = e0*e0 + e1*e1 + e2*e2;

        // Stage to LDS: [tid][j], stride 13 (odd) -> 2-way bank aliasing, free.
        float* lo = lOut + tid * 13;
        lo[0]  = I0;  lo[1]  = I1;  lo[2]  = I2;  lo[3]  = I3;
        lo[4]  = I4;  lo[5]  = I5;  lo[6]  = I6;  lo[7]  = I7;
        lo[8]  = I8;  lo[9]  = I9;  lo[10] = I10; lo[11] = I11;
        lo[12] = I12;
    }
    __syncthreads();

    // Coalesced writeback: block's output region is contiguous
    // [block_base*13, block_base*13 + 3328). 13 wave-contiguous dword stores.
    int total = (n_points - block_base) * 13;
    if (total > 3328) total = 3328;
    size_t gbase = (size_t)block_base * 13;
    #pragma unroll
    for (int c = 0; c < 13; ++c) {
        int idx = c * 256 + tid;
        if (idx < total) out[gbase + idx] = lOut[idx];
    }
}

extern "C" void kernel_launch(void* const* d_in, const int* in_sizes, int n_in,
                              void* d_out, int out_size, void* d_ws, size_t ws_size,
                              hipStream_t stream) {
    const float* tf  = (const float*)d_in[0];
    const float* C2g = (const float*)d_in[1];
    const float* C3g = (const float*)d_in[2];
    float* out = (float*)d_out;
    int n_points = in_sizes[0] / 16;

    int block = 256;
    int grid = (n_points + block - 1) / block;
    hop_invariant_kernel<<<grid, block, 0, stream>>>(tf, C2g, C3g, out, n_points);
}